// Round 8
// baseline (99.848 us; speedup 1.0000x reference)
//
#include <hip/hip_runtime.h>
#include <math.h>

// Chamfer loss, B=32, N=2048, 3 used components.
// R7: R6 (32x32x16 MFMA, K=16 split-bf16 slots, verified absmax 0) plus:
//  - col-split x2 within each block: wave w -> rowgroup w>>1 (32 rows),
//    colhalf w&1 (1024 cols). Grid 1024 -> 2048 blocks (4 -> 8 blocks/CU).
//    Partial row-mins merged via 128-entry LDS in the fused epilogue.
//  - depth-2 pair prefetch (4 B-tiles in flight, wrapped tail index).
// Slot algebra: d2 = A(p).B(q), A/B share K-placement (lane>>5 = K-half both
// sides) -> HW K-permutation cancels. C/D: col=lane&31,
// row=(reg&3)+8*(reg>>2)+4*(lane>>5)  [HW-verified].

#define NPTS   2048
#define NBATCH 32
#define NSIDE  (NBATCH * NPTS)       // 65536 points per cloud
#define SLAB32 (NSIDE * 2)           // uint4 elements per slab (32 B/point)
#define EPSF   1e-16f
#define BIGF   3.4e38f

typedef short bf16x8  __attribute__((ext_vector_type(8)));
typedef float f32x16  __attribute__((ext_vector_type(16)));

__device__ __forceinline__ short f2b(float f) {          // fp32 -> bf16 RNE
    unsigned u = __float_as_uint(f);
    return (short)((u + 0x7FFFu + ((u >> 16) & 1u)) >> 16);
}
__device__ __forceinline__ float b2f(short h) {
    return __uint_as_float(((unsigned)(unsigned short)h) << 16);
}
__device__ __forceinline__ float min3f(float a, float b, float c) {
    return fminf(fminf(a, b), c);    // -> v_min3_f32
}

// ws layout (uint4): [0,S) A_P ; [S,2S) A_Q ; [2S,3S) B_Q ; [3S,4S) B_P.
__global__ __launch_bounds__(256) void chamfer_prep(
    const float* __restrict__ P, const float* __restrict__ Q,
    uint4* __restrict__ ws)
{
    const int i    = blockIdx.x * 256 + threadIdx.x;   // 0..131071
    const int side = i >> 16;                          // 0 = P, 1 = Q
    const int pt   = i & (NSIDE - 1);

    float4 v = ((const float4*)(side ? Q : P))[pt];    // P base == p[0]
    const float cx = v.y, cy = v.z, cz = v.w;
    const short one = f2b(1.0f);

    float n2 = cx * cx + cy * cy + cz * cz;
    short n2h = f2b(n2); short n2l = f2b(n2 - b2f(n2h));
    float tx = -2.f * cx; short mhx = f2b(tx); short mlx = f2b(tx - b2f(mhx));
    float ty = -2.f * cy; short mhy = f2b(ty); short mly = f2b(ty - b2f(mhy));
    float tz = -2.f * cz; short mhz = f2b(tz); short mlz = f2b(tz - b2f(mhz));
    short qhx = f2b(cx), qlx = f2b(cx - b2f(qhx));
    short qhy = f2b(cy), qly = f2b(cy - b2f(qhy));
    short qhz = f2b(cz), qlz = f2b(cz - b2f(qhz));

    __align__(16) short a16[16] = { n2h, n2l, one, one,
                                    mhx, mhy, mhz, mhx, mhy, mhz,
                                    mlx, mly, mlz, mlx, mly, mlz };
    __align__(16) short b16[16] = { one, one, n2h, n2l,
                                    qhx, qhy, qhz, qlx, qly, qlz,
                                    qhx, qhy, qhz, qlx, qly, qlz };

    uint4* A = ws + (size_t)side * SLAB32 + (size_t)pt * 2;
    A[0] = ((const uint4*)a16)[0];
    A[1] = ((const uint4*)a16)[1];
    uint4* B = ws + (size_t)(side ? 2 : 3) * SLAB32 + (size_t)pt * 2;
    B[0] = ((const uint4*)b16)[0];
    B[1] = ((const uint4*)b16)[1];
}

__global__ __launch_bounds__(256) void chamfer_main(
    const uint4* __restrict__ ws, float* __restrict__ out)
{
    __shared__ float srow[4][32];        // per-wave partial row minima
    const int tid  = threadIdx.x;
    const int w    = tid >> 6;
    const int lane = tid & 63;
    const int l31  = lane & 31;
    const int kh   = lane >> 5;          // K-half 0/1 (same role in A & B)
    const int rg   = w >> 1;             // rowgroup 0/1 (32 rows each)
    const int ch   = w & 1;              // colhalf 0/1 (1024 cols each)

    // XCD swizzle: bid&7 pins a batch's blocks to one XCD's L2
    const int bid  = blockIdx.x;               // 0..2047
    const int b    = (bid & 7) | (((bid >> 3) & 3) << 3);
    const int rest = bid >> 5;                 // 0..63
    const int dir  = rest & 1;                 // 0: rows=P/cols=Q ; 1: reverse
    const int bi   = rest >> 1;                // 0..31 : 64-row block

    const uint4* Aslab = ws + (size_t)dir * SLAB32;
    const uint4* Bslab = ws + (size_t)(dir ? 3 : 2) * SLAB32;
    const size_t pbase = (size_t)b * NPTS;

    // ---- A fragment: 32 rows at bi*64 + rg*32, row = l31
    bf16x8 Af = *(const bf16x8*)&Aslab[(pbase + bi * 64 + rg * 32 + l31) * 2 + kh];

    float rm[16];
    #pragma unroll
    for (int i = 0; i < 16; ++i) rm[i] = BIGF;

    const f32x16 z = {0.f,0.f,0.f,0.f, 0.f,0.f,0.f,0.f,
                      0.f,0.f,0.f,0.f, 0.f,0.f,0.f,0.f};

    // ---- main loop: 32 col-tiles (this half), pairs, depth-2 prefetch
    const uint4* Bp = &Bslab[(pbase + ch * 1024 + l31) * 2 + kh]; // tile t at +t*64
    bf16x8 b0 = *(const bf16x8*)(Bp);
    bf16x8 b1 = *(const bf16x8*)(Bp + 64);
    bf16x8 b2 = *(const bf16x8*)(Bp + 128);
    bf16x8 b3 = *(const bf16x8*)(Bp + 192);
    #pragma unroll 4
    for (int t = 0; t < 32; t += 2) {
        const int tn = (t + 4) & 31;           // wrapped tail: dead prefetch
        bf16x8 n0 = *(const bf16x8*)(Bp + tn * 64);
        bf16x8 n1 = *(const bf16x8*)(Bp + tn * 64 + 64);
        f32x16 c0 = __builtin_amdgcn_mfma_f32_32x32x16_bf16(Af, b0, z, 0, 0, 0);
        f32x16 c1 = __builtin_amdgcn_mfma_f32_32x32x16_bf16(Af, b1, z, 0, 0, 0);
        #pragma unroll
        for (int i = 0; i < 16; ++i) rm[i] = min3f(rm[i], c0[i], c1[i]);
        b0 = b2; b1 = b3; b2 = n0; b3 = n1;
    }

    // ---- per-wave: reduce over 32 col-lanes, write 32 partial row-mins
    #pragma unroll
    for (int i = 0; i < 16; ++i) {
        float v = rm[i];
        v = fminf(v, __shfl_xor(v, 1));
        v = fminf(v, __shfl_xor(v, 2));
        v = fminf(v, __shfl_xor(v, 4));
        v = fminf(v, __shfl_xor(v, 8));
        v = fminf(v, __shfl_xor(v, 16));
        if (l31 == 0)
            srow[w][(i & 3) + 8 * (i >> 2) + 4 * kh] = v;
    }
    __syncthreads();

    // ---- merge colhalves, fused sqrt-sum, one atomicAdd per block
    if (tid < 64) {
        const int g = tid >> 5, r = tid & 31;
        float v = fminf(srow[2 * g][r], srow[2 * g + 1][r]);
        float s = sqrtf(fmaxf(v, 0.f) + EPSF);
        #pragma unroll
        for (int off = 32; off > 0; off >>= 1) s += __shfl_down(s, off);
        if (tid == 0) atomicAdd(out, 0.5f * s);
    }
}

extern "C" void kernel_launch(void* const* d_in, const int* in_sizes, int n_in,
                              void* d_out, int out_size, void* d_ws, size_t ws_size,
                              hipStream_t stream) {
    const float* P = (const float*)d_in[0];   // p[0] = first 32*2048*4 floats
    const float* Q = (const float*)d_in[1];
    float* out = (float*)d_out;
    uint4* ws = (uint4*)d_ws;

    hipMemsetAsync(out, 0, sizeof(float), stream);

    chamfer_prep<<<dim3(512), 256, 0, stream>>>(P, Q, ws);

    chamfer_main<<<dim3(2048), 256, 0, stream>>>(ws, out);
}